// Round 2
// baseline (105.056 us; speedup 1.0000x reference)
//
#include <hip/hip_runtime.h>
#include <stdint.h>

// DigitCaps with O=1: routing softmax over one out-capsule is identity, so
// the reference reduces to
//   s[b,v]  = sum_{i,d} W[i,v,d] * x[b,i,d]        (M=32, N=512, K=32768 GEMM)
//   out     = s * sqrt(sq)/(1+sq),  sq = sum_v s^2  (per-b squash)
// Both tuple outputs (t, outputs) are identical [32,1,512] tensors.
//
// R18 = R17 with the l13 residual typo fixed (xb1.y -> xb1.w).
// R17: fuse x_prep into caps_mfma. The hi/lo f16 split of x is done on the
// fly from raw fp32 x (lane ln32 = row b, 32 B per 8-k group), which
// removes one dispatch + 8 MB of HBM round-trip (xh/xl write+read). VMEM
// count per wave unchanged (8 x float4 in flight = 32 VGPR dests), so the
// KSW=32 / 2-block-per-CU schedule from the R14 sweep is preserved.
// x (4 MB) is L2-resident across the 16 vg-block reuse.
// Remaining structure: ~83us harness 0xAA fills + ~10.5us W stream +
// ~3us finish/gaps.

#define NB 32
#define NI 4096
#define NV 512
#define ND 8
#define NK 32768            // K = NI*ND
#define KB 64               // k-blocks (partial slices)
#define KSB (NK / KB)       // 512 k per block (16 waves x 32)
#define KSW 32              // 32 k per wave = two 32x32x16 MFMA steps

typedef __fp16 f16x8 __attribute__((ext_vector_type(8)));
typedef __fp16 f16x2 __attribute__((ext_vector_type(2)));
typedef float  f32x16 __attribute__((ext_vector_type(16)));

// ---------------------------------------------------------------------------
// Kernel 1: partial_h[kb][b][v] (f16) = sum over 512-k slice of x*W.
// Grid: kb(64) x vg(16) = 1024 blocks of 1024 threads (16 waves).
// Wave w owns k = kb*512 + w*32: straight-line 2 ksteps, 8 VMEM
// (4 W float4 + 4 x float4) issued together; x split hi/lo in-register;
// 4 MFMAs (hi+lo per kstep). Epilogue: 16-wave LDS k-reduce -> one f16
// 32x32 tile per block.
// ---------------------------------------------------------------------------
__global__ __launch_bounds__(1024) void caps_mfma(
    const float* __restrict__ W, const float* __restrict__ x,
    __fp16* __restrict__ partial_h)
{
    const int t    = threadIdx.x;
    const int lane = t & 63;
    const int wave = t >> 6;       // 0..15
    const int half = lane >> 5;    // 0/1: which 8-k group of a 16-k step
    const int ln32 = lane & 31;

    const int kb = blockIdx.x & (KB - 1);
    const int vg = blockIdx.x >> 6;
    const int v0 = vg * 32;
    const int k0 = kb * KSB + wave * KSW;
    const int g0 = (k0 >> 3) + half;     // k-group for kstep 0
    const int g1 = g0 + 2;               // k-group for kstep 1

    const float4* xp0 = (const float4*)(x + (size_t)ln32 * NK + (size_t)g0 * 8);
    const float4* xp1 = (const float4*)(x + (size_t)ln32 * NK + (size_t)g1 * 8);
    const float4* wp0 = (const float4*)(W + ((size_t)g0 * NV + v0 + ln32) * ND);
    const float4* wp1 = (const float4*)(W + ((size_t)g1 * NV + v0 + ln32) * ND);

    // 8 VMEM issue back-to-back (straight-line, no loop to sink across)
    const float4 w00 = wp0[0];
    const float4 w01 = wp0[1];
    const float4 w10 = wp1[0];
    const float4 w11 = wp1[1];
    const float4 xa0 = xp0[0];
    const float4 xa1 = xp0[1];
    const float4 xb0 = xp1[0];
    const float4 xb1 = xp1[1];

    // W -> f16 (single plane; |W|~0.01 so rtz rel err 2^-11 is enough)
    const f16x2 p01 = __builtin_amdgcn_cvt_pkrtz(w00.x, w00.y);
    const f16x2 p23 = __builtin_amdgcn_cvt_pkrtz(w00.z, w00.w);
    const f16x2 p45 = __builtin_amdgcn_cvt_pkrtz(w01.x, w01.y);
    const f16x2 p67 = __builtin_amdgcn_cvt_pkrtz(w01.z, w01.w);
    const f16x8 b0 = {p01.x, p01.y, p23.x, p23.y, p45.x, p45.y, p67.x, p67.y};
    const f16x2 q01 = __builtin_amdgcn_cvt_pkrtz(w10.x, w10.y);
    const f16x2 q23 = __builtin_amdgcn_cvt_pkrtz(w10.z, w10.w);
    const f16x2 q45 = __builtin_amdgcn_cvt_pkrtz(w11.x, w11.y);
    const f16x2 q67 = __builtin_amdgcn_cvt_pkrtz(w11.z, w11.w);
    const f16x8 b1 = {q01.x, q01.y, q23.x, q23.y, q45.x, q45.y, q67.x, q67.y};

    // x -> hi/lo f16 planes, in-register (bit-identical to old x_prep)
    const f16x2 h00 = __builtin_amdgcn_cvt_pkrtz(xa0.x, xa0.y);
    const f16x2 h01 = __builtin_amdgcn_cvt_pkrtz(xa0.z, xa0.w);
    const f16x2 h02 = __builtin_amdgcn_cvt_pkrtz(xa1.x, xa1.y);
    const f16x2 h03 = __builtin_amdgcn_cvt_pkrtz(xa1.z, xa1.w);
    const f16x2 l00 = __builtin_amdgcn_cvt_pkrtz(xa0.x - (float)h00.x, xa0.y - (float)h00.y);
    const f16x2 l01 = __builtin_amdgcn_cvt_pkrtz(xa0.z - (float)h01.x, xa0.w - (float)h01.y);
    const f16x2 l02 = __builtin_amdgcn_cvt_pkrtz(xa1.x - (float)h02.x, xa1.y - (float)h02.y);
    const f16x2 l03 = __builtin_amdgcn_cvt_pkrtz(xa1.z - (float)h03.x, xa1.w - (float)h03.y);
    const f16x8 a0h = {h00.x, h00.y, h01.x, h01.y, h02.x, h02.y, h03.x, h03.y};
    const f16x8 a0l = {l00.x, l00.y, l01.x, l01.y, l02.x, l02.y, l03.x, l03.y};

    const f16x2 h10 = __builtin_amdgcn_cvt_pkrtz(xb0.x, xb0.y);
    const f16x2 h11 = __builtin_amdgcn_cvt_pkrtz(xb0.z, xb0.w);
    const f16x2 h12 = __builtin_amdgcn_cvt_pkrtz(xb1.x, xb1.y);
    const f16x2 h13 = __builtin_amdgcn_cvt_pkrtz(xb1.z, xb1.w);
    const f16x2 l10 = __builtin_amdgcn_cvt_pkrtz(xb0.x - (float)h10.x, xb0.y - (float)h10.y);
    const f16x2 l11 = __builtin_amdgcn_cvt_pkrtz(xb0.z - (float)h11.x, xb0.w - (float)h11.y);
    const f16x2 l12 = __builtin_amdgcn_cvt_pkrtz(xb1.x - (float)h12.x, xb1.y - (float)h12.y);
    const f16x2 l13 = __builtin_amdgcn_cvt_pkrtz(xb1.z - (float)h13.x, xb1.w - (float)h13.y);
    const f16x8 a1h = {h10.x, h10.y, h11.x, h11.y, h12.x, h12.y, h13.x, h13.y};
    const f16x8 a1l = {l10.x, l10.y, l11.x, l11.y, l12.x, l12.y, l13.x, l13.y};

    f32x16 acc;
#pragma unroll
    for (int r = 0; r < 16; ++r) acc[r] = 0.0f;
    acc = __builtin_amdgcn_mfma_f32_32x32x16_f16(a0h, b0, acc, 0, 0, 0);
    acc = __builtin_amdgcn_mfma_f32_32x32x16_f16(a0l, b0, acc, 0, 0, 0);
    acc = __builtin_amdgcn_mfma_f32_32x32x16_f16(a1h, b1, acc, 0, 0, 0);
    acc = __builtin_amdgcn_mfma_f32_32x32x16_f16(a1l, b1, acc, 0, 0, 0);

    // 16-wave k-reduce via LDS: wave w writes its 32x32 f32 tile, then
    // thread t sums element t across the 16 tiles and stores f16.
    __shared__ float red[16 * 1024];   // 64 KB
#pragma unroll
    for (int r = 0; r < 16; ++r)
        red[wave * 1024 + r * 64 + lane] = acc[r];
    __syncthreads();

    float val = 0.0f;
#pragma unroll
    for (int w = 0; w < 16; ++w)       // 16 independent LDS reads
        val += red[w * 1024 + t];

    const int r  = t >> 6;
    const int ln = t & 63;
    // C/D layout (m74/m101): col = lane&31 (v), row = (reg&3)+8*(reg>>2)+4*(lane>>5) (b)
    const int row = (r & 3) + 8 * (r >> 2) + 4 * (ln >> 5);
    const int col = ln & 31;
    partial_h[((size_t)kb * NB + row) * NV + v0 + col] = (__fp16)val;
}

// ---------------------------------------------------------------------------
// Kernel 2: reduce KB f16 slices + squash + write both outputs.
// Grid: 32 blocks (one per b) x 1024 threads. Thread t: v = t&511,
// kb-half = t>>9 (32 slices each) -> 2-way MLP; LDS combine; squash.
// ---------------------------------------------------------------------------
__global__ __launch_bounds__(1024) void caps_finish(
    const __fp16* __restrict__ partial_h, float* __restrict__ out)
{
    const int t = threadIdx.x;
    const int v = t & 511;
    const int h = t >> 9;              // 0/1: which half of the kb range
    const int b = blockIdx.x;

    float s = 0.0f;
#pragma unroll
    for (int g = 0; g < KB / 2; ++g)   // 32 independent coalesced loads
        s += (float)partial_h[((size_t)(h * (KB / 2) + g) * NB + b) * NV + v];

    __shared__ float sv[1024];
    sv[t] = s;
    __syncthreads();

    float sq = 0.0f;
    float stot = 0.0f;
    if (t < 512) {
        stot = sv[t] + sv[t + 512];
        sq = stot * stot;
    }
#pragma unroll
    for (int off = 32; off > 0; off >>= 1)
        sq += __shfl_xor(sq, off, 64);

    __shared__ float red[16];
    if ((t & 63) == 0) red[t >> 6] = sq;
    __syncthreads();
    if (t < 512) {
        float tot = 0.0f;
#pragma unroll
        for (int wv = 0; wv < 16; ++wv) tot += red[wv];  // waves 8..15 wrote 0

        // squash factor: sq/((1+sq)*sqrt(sq)) == sqrt(sq)/(1+sq)
        const float factor = sqrtf(tot) / (1.0f + tot);
        const float r = stot * factor;

        out[(size_t)b * NV + v]           = r;  // output 0: t       [B,1,V]
        out[NB * NV + (size_t)b * NV + v] = r;  // output 1: outputs [B,O,V]
    }
}

extern "C" void kernel_launch(void* const* d_in, const int* in_sizes, int n_in,
                              void* d_out, int out_size, void* d_ws, size_t ws_size,
                              hipStream_t stream) {
    const float* x = (const float*)d_in[0];   // [32, 4096, 8]
    const float* W = (const float*)d_in[1];   // [1, 4096, 512, 8]
    float* out     = (float*)d_out;           // 2 x [32,1,512] concatenated

    __fp16* partialh = (__fp16*)d_ws;         // 2 MB (f16, KB=64)

    caps_mfma<<<KB * 16, 1024, 0, stream>>>(W, x, partialh);
    caps_finish<<<NB, 1024, 0, stream>>>(partialh, out);
}

// Round 3
// 100.582 us; speedup vs baseline: 1.0445x; 1.0445x over previous
//
#include <hip/hip_runtime.h>
#include <stdint.h>

// DigitCaps with O=1: routing softmax over one out-capsule is identity, so
// the reference reduces to
//   s[b,v]  = sum_{i,d} W[i,v,d] * x[b,i,d]        (M=32, N=512, K=32768 GEMM)
//   out     = s * sqrt(sq)/(1+sq),  sq = sum_v s^2  (per-b squash)
// Both tuple outputs (t, outputs) are identical [32,1,512] tensors.
//
// R19: fusion kept, but x is staged through LDS in fragment order.
// R18's direct x loads were a 32-segment gather (lane = row, 128 KB row
// pitch) that cost as much as the removed x_prep round-trip saved. Now
// phase 1 loads the block's 64 KB x slice coalesced (512-B row segments),
// splits hi/lo in-register, and writes XOR-swizzled fragment-order LDS;
// phase 2 ds_read_b128's the fragments and runs the same 4-MFMA core with
// W streamed from global (issued first, hidden under staging). The reduce
// reuses the same 64 KB LDS, keeping 2 blocks/CU.

#define NB 32
#define NI 4096
#define NV 512
#define ND 8
#define NK 32768            // K = NI*ND
#define KB 64               // k-blocks (partial slices)
#define KSB (NK / KB)       // 512 k per block (16 waves x 32)
#define KSW 32              // 32 k per wave = two 32x32x16 MFMA steps

typedef __fp16 f16x8 __attribute__((ext_vector_type(8)));
typedef __fp16 f16x4 __attribute__((ext_vector_type(4)));
typedef __fp16 f16x2 __attribute__((ext_vector_type(2)));
typedef float  f32x16 __attribute__((ext_vector_type(16)));

// ---------------------------------------------------------------------------
// Kernel 1: partial_h[kb][b][v] (f16) = sum over 512-k slice of x*W.
// Grid: kb(64) x vg(16) = 1024 blocks of 1024 threads (16 waves).
// Phase 1: coalesced x stage -> hi/lo f16 fragment-order LDS (swizzled).
// Phase 2: per-wave ds_read_b128 frags + 4 W float4 global + 4 MFMAs.
// Phase 3: 16-wave LDS k-reduce (reusing the stage buffer) -> f16 tile.
// ---------------------------------------------------------------------------
__global__ __launch_bounds__(1024) void caps_mfma(
    const float* __restrict__ W, const float* __restrict__ x,
    __fp16* __restrict__ partial_h)
{
    const int t    = threadIdx.x;
    const int lane = t & 63;
    const int wave = t >> 6;       // 0..15
    const int half = lane >> 5;    // 0/1: which 8-k group of a 16-k step
    const int ln32 = lane & 31;

    const int kb = blockIdx.x & (KB - 1);
    const int vg = blockIdx.x >> 6;
    const int v0 = vg * 32;

    const int g0l = wave * 4 + half;     // local k-group for kstep 0 (0..63)
    const int g1l = g0l + 2;             // local k-group for kstep 1
    const int g0  = kb * (KSB / 8) + g0l;  // global k-group
    const int g1  = g0 + 2;

    // W loads issued first: HBM latency hides under the x staging below.
    const float4* wp0 = (const float4*)(W + ((size_t)g0 * NV + v0 + ln32) * ND);
    const float4* wp1 = (const float4*)(W + ((size_t)g1 * NV + v0 + ln32) * ND);
    const float4 w00 = wp0[0];
    const float4 w01 = wp0[1];
    const float4 w10 = wp1[0];
    const float4 w11 = wp1[1];

    // ---- Phase 1: stage x slice [32 rows][512 k] -> fragment-order LDS ----
    // Plane layout (f16 elems): [gp 0..63][slot] where slot = 32 rows x 8 k,
    // swizzled: eoff = gp*256 + ((r*8 + part*4) ^ ((gp&7)<<3)).
    // Writes: lanes sweep gp -> XOR spreads slots, ~2-way banks (free).
    // Reads: gp wave-uniform -> XOR is a constant slot permutation, clean.
    __shared__ __align__(16) __fp16 xs[2 * 16384];   // hi plane, lo plane: 64 KB

    const int r = t >> 5;              // x row 0..31
    const int c = t & 31;
    const float* xrow = x + (size_t)r * NK + (size_t)kb * KSB;
#pragma unroll
    for (int j = 0; j < 4; ++j) {
        const int kl = (c + 32 * j) * 4;          // k offset in slice, step 4
        const float4 f = *(const float4*)(xrow + kl);   // coalesced 512-B segs
        const int gp   = kl >> 3;                 // local k-group 0..63
        const int part = (kl >> 2) & 1;           // low/high half of group
        const f16x2 hA = __builtin_amdgcn_cvt_pkrtz(f.x, f.y);
        const f16x2 hB = __builtin_amdgcn_cvt_pkrtz(f.z, f.w);
        const f16x2 lA = __builtin_amdgcn_cvt_pkrtz(f.x - (float)hA.x, f.y - (float)hA.y);
        const f16x2 lB = __builtin_amdgcn_cvt_pkrtz(f.z - (float)hB.x, f.w - (float)hB.y);
        const int eoff = gp * 256 + ((r * 8 + part * 4) ^ ((gp & 7) << 3));
        *(f16x4*)(xs + eoff)         = (f16x4){hA.x, hA.y, hB.x, hB.y};
        *(f16x4*)(xs + 16384 + eoff) = (f16x4){lA.x, lA.y, lB.x, lB.y};
    }
    __syncthreads();

    // ---- Phase 2: fragment reads + MFMA ----
    const int e0 = g0l * 256 + ((ln32 * 8) ^ ((g0l & 7) << 3));
    const int e1 = g1l * 256 + ((ln32 * 8) ^ ((g1l & 7) << 3));
    const f16x8 a0h = *(const f16x8*)(xs + e0);
    const f16x8 a0l = *(const f16x8*)(xs + 16384 + e0);
    const f16x8 a1h = *(const f16x8*)(xs + e1);
    const f16x8 a1l = *(const f16x8*)(xs + 16384 + e1);

    // W -> f16 (single plane; |W|~0.01 so rtz rel err 2^-11 is enough)
    const f16x2 p01 = __builtin_amdgcn_cvt_pkrtz(w00.x, w00.y);
    const f16x2 p23 = __builtin_amdgcn_cvt_pkrtz(w00.z, w00.w);
    const f16x2 p45 = __builtin_amdgcn_cvt_pkrtz(w01.x, w01.y);
    const f16x2 p67 = __builtin_amdgcn_cvt_pkrtz(w01.z, w01.w);
    const f16x8 b0 = {p01.x, p01.y, p23.x, p23.y, p45.x, p45.y, p67.x, p67.y};
    const f16x2 q01 = __builtin_amdgcn_cvt_pkrtz(w10.x, w10.y);
    const f16x2 q23 = __builtin_amdgcn_cvt_pkrtz(w10.z, w10.w);
    const f16x2 q45 = __builtin_amdgcn_cvt_pkrtz(w11.x, w11.y);
    const f16x2 q67 = __builtin_amdgcn_cvt_pkrtz(w11.z, w11.w);
    const f16x8 b1 = {q01.x, q01.y, q23.x, q23.y, q45.x, q45.y, q67.x, q67.y};

    f32x16 acc;
#pragma unroll
    for (int rr = 0; rr < 16; ++rr) acc[rr] = 0.0f;
    acc = __builtin_amdgcn_mfma_f32_32x32x16_f16(a0h, b0, acc, 0, 0, 0);
    acc = __builtin_amdgcn_mfma_f32_32x32x16_f16(a0l, b0, acc, 0, 0, 0);
    acc = __builtin_amdgcn_mfma_f32_32x32x16_f16(a1h, b1, acc, 0, 0, 0);
    acc = __builtin_amdgcn_mfma_f32_32x32x16_f16(a1l, b1, acc, 0, 0, 0);

    // ---- Phase 3: 16-wave k-reduce, reusing the stage LDS (64 KB) ----
    __syncthreads();                   // all frag reads landed in regs
    float* red = (float*)xs;           // 16 * 1024 floats
#pragma unroll
    for (int rr = 0; rr < 16; ++rr)
        red[wave * 1024 + rr * 64 + lane] = acc[rr];
    __syncthreads();

    float val = 0.0f;
#pragma unroll
    for (int w = 0; w < 16; ++w)       // 16 independent LDS reads
        val += red[w * 1024 + t];

    const int rg = t >> 6;
    const int ln = t & 63;
    // C/D layout (m74/m101): col = lane&31 (v), row = (reg&3)+8*(reg>>2)+4*(lane>>5) (b)
    const int row = (rg & 3) + 8 * (rg >> 2) + 4 * (ln >> 5);
    const int col = ln & 31;
    partial_h[((size_t)kb * NB + row) * NV + v0 + col] = (__fp16)val;
}

// ---------------------------------------------------------------------------
// Kernel 2: reduce KB f16 slices + squash + write both outputs.
// Grid: 32 blocks (one per b) x 1024 threads. Thread t: v = t&511,
// kb-half = t>>9 (32 slices each) -> 2-way MLP; LDS combine; squash.
// ---------------------------------------------------------------------------
__global__ __launch_bounds__(1024) void caps_finish(
    const __fp16* __restrict__ partial_h, float* __restrict__ out)
{
    const int t = threadIdx.x;
    const int v = t & 511;
    const int h = t >> 9;              // 0/1: which half of the kb range
    const int b = blockIdx.x;

    float s = 0.0f;
#pragma unroll
    for (int g = 0; g < KB / 2; ++g)   // 32 independent coalesced loads
        s += (float)partial_h[((size_t)(h * (KB / 2) + g) * NB + b) * NV + v];

    __shared__ float sv[1024];
    sv[t] = s;
    __syncthreads();

    float sq = 0.0f;
    float stot = 0.0f;
    if (t < 512) {
        stot = sv[t] + sv[t + 512];
        sq = stot * stot;
    }
#pragma unroll
    for (int off = 32; off > 0; off >>= 1)
        sq += __shfl_xor(sq, off, 64);

    __shared__ float red[16];
    if ((t & 63) == 0) red[t >> 6] = sq;
    __syncthreads();
    if (t < 512) {
        float tot = 0.0f;
#pragma unroll
        for (int wv = 0; wv < 16; ++wv) tot += red[wv];  // waves 8..15 wrote 0

        // squash factor: sq/((1+sq)*sqrt(sq)) == sqrt(sq)/(1+sq)
        const float factor = sqrtf(tot) / (1.0f + tot);
        const float r = stot * factor;

        out[(size_t)b * NV + v]           = r;  // output 0: t       [B,1,V]
        out[NB * NV + (size_t)b * NV + v] = r;  // output 1: outputs [B,O,V]
    }
}

extern "C" void kernel_launch(void* const* d_in, const int* in_sizes, int n_in,
                              void* d_out, int out_size, void* d_ws, size_t ws_size,
                              hipStream_t stream) {
    const float* x = (const float*)d_in[0];   // [32, 4096, 8]
    const float* W = (const float*)d_in[1];   // [1, 4096, 512, 8]
    float* out     = (float*)d_out;           // 2 x [32,1,512] concatenated

    __fp16* partialh = (__fp16*)d_ws;         // 2 MB (f16, KB=64)

    caps_mfma<<<KB * 16, 1024, 0, stream>>>(W, x, partialh);
    caps_finish<<<NB, 1024, 0, stream>>>(partialh, out);
}